// Round 12
// baseline (232.787 us; speedup 1.0000x reference)
//
#include <hip/hip_runtime.h>

#define BATCH   1024
#define MAXLEN  200
#define KCAPS   8
#define INU     256
#define OUTU    256
#define NEGPAD  -65535.0f
#define HSTR    264   // padded LDS row stride (floats)

typedef _Float16 f16;
typedef _Float16 f16x8 __attribute__((ext_vector_type(8)));
typedef float    f32x4 __attribute__((ext_vector_type(4)));

// ---------------- prep: Bcur copy + packed-frag S and S^T (hi/lo f16) ------
// packed idx = ((ks*16+nf)*64+lane)*8+j  <->  M[k = ks*32+(lane>>4)*8+j][n = nf*16+(lane&15)]
__global__ void k_prep(const float* __restrict__ S, const float* __restrict__ Bm,
                       f16* __restrict__ Shi, f16* __restrict__ Slo,
                       f16* __restrict__ Thi, f16* __restrict__ Tlo,
                       float* __restrict__ Bcur) {
    int idx = blockIdx.x * 256 + threadIdx.x;    // 0 .. 65535
    if (idx < KCAPS * MAXLEN) Bcur[idx] = Bm[idx];
    int j    = idx & 7;
    int lane = (idx >> 3) & 63;
    int nf   = (idx >> 9) & 15;
    int ks   = idx >> 13;
    int k = ks * 32 + (lane >> 4) * 8 + j;
    int n = nf * 16 + (lane & 15);
    float vS = S[k * 256 + n];
    f16 hS = (f16)vS;
    Shi[idx] = hS;
    Slo[idx] = (f16)(vS - (float)hS);
    float vT = S[n * 256 + k];
    f16 hT = (f16)vT;
    Thi[idx] = hT;
    Tlo[idx] = (f16)(vT - (float)hT);
}

// ---------------- fused per-iteration kernel --------------------------------
// Per batch b (1024 blocks x 512 thr):
//   A: W = softmax_l(mask(Bcur))                    (wave per k)
//   B: G[k,e]  = sum_l W[k,l]*low[b,l,e]            (fp32 VALU, masked l)
//   C: hp[k,o] = sum_e G[k,e]*S[e,o]   (MFMA)  -> squash -> high
//   do_T=0: out = high, return.
//   D: T[k,e]  = sum_o high[k,o]*S[e,o] (MFMA)
//   E: delta_T[l][k] = sum_e low[l,e]*T[k,e] (MFMA) -> partials[k*200+l][b]
// LDS: Wl + one 16.9KB buffer serving Gl -> Hl -> Tl (aliased, barriered) + Sl.
__global__ __launch_bounds__(512, 6) void k_G(const float* __restrict__ Bcur,
                                              const int*   __restrict__ seq_len,
                                              const float* __restrict__ low,
                                              const f16*   __restrict__ Shi,
                                              const f16*   __restrict__ Slo,
                                              const f16*   __restrict__ Thi,
                                              const f16*   __restrict__ Tlo,
                                              float*       __restrict__ partials,
                                              float*       __restrict__ out,
                                              int do_T) {
    __shared__ float Wl[KCAPS * MAXLEN];   // 6.4 KB
    __shared__ float GH[16 * HSTR];        // 16.9 KB: Gl -> Hl -> Tl (rows 8..15 stay 0)
    __shared__ float Sl[KCAPS * 256];      // 8 KB cross-group reduce slab
    const int b   = blockIdx.x;
    const int tid = threadIdx.x;
    const int len = seq_len[b];

    for (int i = tid; i < KCAPS * MAXLEN; i += 512) Wl[i] = Bcur[i];
    for (int i = tid; i < 16 * HSTR; i += 512) GH[i] = 0.f;
    __syncthreads();

    // phase A: masked softmax, one 64-lane wave per k
    {
        const int k  = tid >> 6;
        const int ln = tid & 63;
        float m = -3.4e38f;
        for (int l = ln; l < MAXLEN; l += 64) {
            float v = (l < len) ? Wl[k * MAXLEN + l] : NEGPAD;
            m = fmaxf(m, v);
        }
        #pragma unroll
        for (int off = 32; off >= 1; off >>= 1) m = fmaxf(m, __shfl_xor(m, off));
        float ssum = 0.f;
        for (int l = ln; l < MAXLEN; l += 64) {
            float v = (l < len) ? Wl[k * MAXLEN + l] : NEGPAD;
            ssum += __expf(v - m);
        }
        #pragma unroll
        for (int off = 32; off >= 1; off >>= 1) ssum += __shfl_xor(ssum, off);
        float inv = 1.f / ssum;
        for (int l = ln; l < MAXLEN; l += 64) {
            float v = (l < len) ? Wl[k * MAXLEN + l] : NEGPAD;
            Wl[k * MAXLEN + l] = __expf(v - m) * inv;
        }
    }
    __syncthreads();

    const float* lb = low + (size_t)b * (MAXLEN * INU);
    const int o  = tid & 255;
    const int lg = tid >> 8;

    // phase B: G[k,o] = sum_l W[k,l]*low[l,o]; lg groups interleave 4-l chunks
    const int lim = (len == 0) ? MAXLEN : len;   // W==0 for l>=len when len>0
    {
        float g[KCAPS];
        #pragma unroll
        for (int k = 0; k < KCAPS; k++) g[k] = 0.f;
        for (int l4 = lg * 4; l4 < lim; l4 += 8) {   // max l4=196 -> reads l<=199 safe
            float v0 = lb[(l4 + 0) * INU + o];
            float v1 = lb[(l4 + 1) * INU + o];
            float v2 = lb[(l4 + 2) * INU + o];
            float v3 = lb[(l4 + 3) * INU + o];
            #pragma unroll
            for (int k = 0; k < KCAPS; k++) {
                const float4 w = *reinterpret_cast<const float4*>(&Wl[k * MAXLEN + l4]);
                g[k] = fmaf(w.x, v0, g[k]);
                g[k] = fmaf(w.y, v1, g[k]);
                g[k] = fmaf(w.z, v2, g[k]);
                g[k] = fmaf(w.w, v3, g[k]);
            }
        }
        if (lg == 1) {
            #pragma unroll
            for (int k = 0; k < KCAPS; k++) Sl[k * 256 + o] = g[k];
        }
        __syncthreads();
        if (lg == 0) {
            #pragma unroll
            for (int k = 0; k < KCAPS; k++) GH[k * HSTR + o] = g[k] + Sl[k * 256 + o];
        }
    }
    __syncthreads();

    // phase C (MFMA): hp[k][o] = sum_e G[k][e]*S[e][o]; wave wv -> nf = 2wv, 2wv+1
    const int wv = tid >> 6, lane = tid & 63;
    const int r15 = lane & 15, q = lane >> 4;
    f32x4 aC[2];
    aC[0] = (f32x4){0.f, 0.f, 0.f, 0.f};
    aC[1] = (f32x4){0.f, 0.f, 0.f, 0.f};
    #pragma unroll
    for (int ks = 0; ks < 8; ks++) {
        const float* gp = &GH[r15 * HSTR + ks * 32 + q * 8];
        f32x4 a0 = *reinterpret_cast<const f32x4*>(gp);
        f32x4 a1 = *reinterpret_cast<const f32x4*>(gp + 4);
        f16x8 ah, al;
        #pragma unroll
        for (int j = 0; j < 4; j++) {
            f16 t = (f16)a0[j]; ah[j] = t; al[j] = (f16)(a0[j] - (float)t);
        }
        #pragma unroll
        for (int j = 0; j < 4; j++) {
            f16 t = (f16)a1[j]; ah[4 + j] = t; al[4 + j] = (f16)(a1[j] - (float)t);
        }
        #pragma unroll
        for (int i = 0; i < 2; i++) {
            const int nf = wv * 2 + i;
            f16x8 bh = *reinterpret_cast<const f16x8*>(Shi + (ks * 16 + nf) * 512 + lane * 8);
            f16x8 bl = *reinterpret_cast<const f16x8*>(Slo + (ks * 16 + nf) * 512 + lane * 8);
            aC[i] = __builtin_amdgcn_mfma_f32_16x16x32_f16(ah, bh, aC[i], 0, 0, 0);
            aC[i] = __builtin_amdgcn_mfma_f32_16x16x32_f16(al, bh, aC[i], 0, 0, 0);
            aC[i] = __builtin_amdgcn_mfma_f32_16x16x32_f16(ah, bl, aC[i], 0, 0, 0);
        }
    }
    // squash: thread holds hp[k=q*4+r][o=(2wv+i)*16+r15]; k<8 lives in q=0,1
    float s0, s1;
    {
        float n0 = aC[0][0]*aC[0][0] + aC[0][1]*aC[0][1] + aC[0][2]*aC[0][2] + aC[0][3]*aC[0][3];
        float n1 = aC[1][0]*aC[1][0] + aC[1][1]*aC[1][1] + aC[1][2]*aC[1][2] + aC[1][3]*aC[1][3];
        n0 += __shfl_xor(n0, 16);
        n1 += __shfl_xor(n1, 16);
        s0 = n0 / (1.f + n0) * (1.f / sqrtf(n0 + 1e-9f));
        s1 = n1 / (1.f + n1) * (1.f / sqrtf(n1 + 1e-9f));
    }
    if (!do_T) {
        if (q < 2) {
            #pragma unroll
            for (int r = 0; r < 4; r++) {
                out[((size_t)b * KCAPS + q * 4 + r) * OUTU + (wv * 2 + 0) * 16 + r15] = s0 * aC[0][r];
                out[((size_t)b * KCAPS + q * 4 + r) * OUTU + (wv * 2 + 1) * 16 + r15] = s1 * aC[1][r];
            }
        }
        return;
    }
    __syncthreads();                       // all phase-C reads of GH done
    if (q < 2) {                           // GH becomes Hl (rows 8..15 still 0)
        #pragma unroll
        for (int r = 0; r < 4; r++) {
            GH[(q * 4 + r) * HSTR + (wv * 2 + 0) * 16 + r15] = s0 * aC[0][r];
            GH[(q * 4 + r) * HSTR + (wv * 2 + 1) * 16 + r15] = s1 * aC[1][r];
        }
    }
    __syncthreads();

    // phase D (MFMA): T[k][e] = sum_o H[k][o]*S[e][o]
    f32x4 aD[2];
    aD[0] = (f32x4){0.f, 0.f, 0.f, 0.f};
    aD[1] = (f32x4){0.f, 0.f, 0.f, 0.f};
    #pragma unroll
    for (int ks = 0; ks < 8; ks++) {
        const float* hp = &GH[r15 * HSTR + ks * 32 + q * 8];
        f32x4 a0 = *reinterpret_cast<const f32x4*>(hp);
        f32x4 a1 = *reinterpret_cast<const f32x4*>(hp + 4);
        f16x8 ah, al;
        #pragma unroll
        for (int j = 0; j < 4; j++) {
            f16 t = (f16)a0[j]; ah[j] = t; al[j] = (f16)(a0[j] - (float)t);
        }
        #pragma unroll
        for (int j = 0; j < 4; j++) {
            f16 t = (f16)a1[j]; ah[4 + j] = t; al[4 + j] = (f16)(a1[j] - (float)t);
        }
        #pragma unroll
        for (int i = 0; i < 2; i++) {
            const int nf = wv * 2 + i;
            f16x8 bh = *reinterpret_cast<const f16x8*>(Thi + (ks * 16 + nf) * 512 + lane * 8);
            f16x8 bl = *reinterpret_cast<const f16x8*>(Tlo + (ks * 16 + nf) * 512 + lane * 8);
            aD[i] = __builtin_amdgcn_mfma_f32_16x16x32_f16(ah, bh, aD[i], 0, 0, 0);
            aD[i] = __builtin_amdgcn_mfma_f32_16x16x32_f16(al, bh, aD[i], 0, 0, 0);
            aD[i] = __builtin_amdgcn_mfma_f32_16x16x32_f16(ah, bl, aD[i], 0, 0, 0);
        }
    }
    __syncthreads();                       // all phase-D reads of GH done
    if (q < 2) {                           // GH becomes Tl (rows 8..15 still 0)
        #pragma unroll
        for (int r = 0; r < 4; r++) {
            GH[(q * 4 + r) * HSTR + (wv * 2 + 0) * 16 + r15] = aD[0][r];
            GH[(q * 4 + r) * HSTR + (wv * 2 + 1) * 16 + r15] = aD[1][r];
        }
    }
    __syncthreads();

    // phase E (MFMA): delta_T[l][k] = sum_e low[l,e]*T[k,e]; 13 M-frags / 8 waves
    const int nfr = (wv < 5) ? 2 : 1;
    f32x4 acc2[2];
    acc2[0] = (f32x4){0.f, 0.f, 0.f, 0.f};
    acc2[1] = (f32x4){0.f, 0.f, 0.f, 0.f};
    for (int ks = 0; ks < 8; ks++) {
        const int ob = ks * 32 + q * 8;
        f32x4 h0 = *reinterpret_cast<const f32x4*>(&GH[r15 * HSTR + ob]);
        f32x4 h1 = *reinterpret_cast<const f32x4*>(&GH[r15 * HSTR + ob + 4]);
        f16x8 bh, bl;
        #pragma unroll
        for (int j = 0; j < 4; j++) {
            f16 t = (f16)h0[j]; bh[j] = t; bl[j] = (f16)(h0[j] - (float)t);
        }
        #pragma unroll
        for (int j = 0; j < 4; j++) {
            f16 t = (f16)h1[j]; bh[4 + j] = t; bl[4 + j] = (f16)(h1[j] - (float)t);
        }
        for (int mi = 0; mi < nfr; mi++) {
            const int mf = wv + mi * 8;
            const int l  = mf * 16 + r15;
            const int lc = (l < MAXLEN) ? l : (MAXLEN - 1);   // clamp: D rows >=200 unwritten
            const float* ap = lb + (size_t)lc * INU + ob;
            float4 v0 = *reinterpret_cast<const float4*>(ap);
            float4 v1 = *reinterpret_cast<const float4*>(ap + 4);
            f16x8 ah, al;
            ah[0] = (f16)v0.x; al[0] = (f16)(v0.x - (float)ah[0]);
            ah[1] = (f16)v0.y; al[1] = (f16)(v0.y - (float)ah[1]);
            ah[2] = (f16)v0.z; al[2] = (f16)(v0.z - (float)ah[2]);
            ah[3] = (f16)v0.w; al[3] = (f16)(v0.w - (float)ah[3]);
            ah[4] = (f16)v1.x; al[4] = (f16)(v1.x - (float)ah[4]);
            ah[5] = (f16)v1.y; al[5] = (f16)(v1.y - (float)ah[5]);
            ah[6] = (f16)v1.z; al[6] = (f16)(v1.z - (float)ah[6]);
            ah[7] = (f16)v1.w; al[7] = (f16)(v1.w - (float)ah[7]);
            acc2[mi] = __builtin_amdgcn_mfma_f32_16x16x32_f16(ah, bh, acc2[mi], 0, 0, 0);
            acc2[mi] = __builtin_amdgcn_mfma_f32_16x16x32_f16(al, bh, acc2[mi], 0, 0, 0);
            acc2[mi] = __builtin_amdgcn_mfma_f32_16x16x32_f16(ah, bl, acc2[mi], 0, 0, 0);
        }
    }
    const int kcol = r15;
    if (kcol < KCAPS) {
        for (int mi = 0; mi < nfr; mi++) {
            const int mf = wv + mi * 8;
            const int lbase = mf * 16 + q * 4;
            #pragma unroll
            for (int r = 0; r < 4; r++) {
                const int l = lbase + r;
                if (l < MAXLEN)
                    partials[(size_t)(kcol * MAXLEN + l) * BATCH + b] = acc2[mi][r];
            }
        }
    }
}

// ---------------- B update: Bcur[i] += sum_b partials[i][b] ----------------
__global__ __launch_bounds__(256) void k_update(const float* __restrict__ partials,
                                                float* __restrict__ Bcur) {
    __shared__ float red[256];
    const int i   = blockIdx.x;
    const int tid = threadIdx.x;
    float s = 0.f;
    #pragma unroll
    for (int j = 0; j < BATCH / 256; j++) s += partials[(size_t)i * BATCH + tid + j * 256];
    red[tid] = s;
    __syncthreads();
    for (int st = 128; st > 0; st >>= 1) {
        if (tid < st) red[tid] += red[tid + st];
        __syncthreads();
    }
    if (tid == 0) Bcur[i] += red[0];
}

extern "C" void kernel_launch(void* const* d_in, const int* in_sizes, int n_in,
                              void* d_out, int out_size, void* d_ws, size_t ws_size,
                              hipStream_t stream) {
    const float* low = (const float*)d_in[0];
    const float* S   = (const float*)d_in[1];
    const float* Bm  = (const float*)d_in[2];
    const int*   seq = (const int*)d_in[3];
    float* out = (float*)d_out;

    char* ws = (char*)d_ws;
    float* Bcur     = (float*)ws;                     // 6,400 B
    float* partials = (float*)(ws + 6400);            // 6,553,600 B
    f16*   Shi      = (f16*)(ws + 6560000);           // 131,072 B
    f16*   Slo      = (f16*)(ws + 6691072);           // 131,072 B
    f16*   Thi      = (f16*)(ws + 6822144);           // 131,072 B
    f16*   Tlo      = (f16*)(ws + 6953216);           // 131,072 B

    k_prep<<<256, 256, 0, stream>>>(S, Bm, Shi, Slo, Thi, Tlo, Bcur);
    for (int it = 0; it < 3; it++) {
        int last = (it == 2);
        k_G<<<BATCH, 512, 0, stream>>>(Bcur, seq, low, Shi, Slo, Thi, Tlo,
                                       partials, out, last ? 0 : 1);
        if (!last) k_update<<<KCAPS * MAXLEN, 256, 0, stream>>>(partials, Bcur);
    }
}

// Round 13
// 227.685 us; speedup vs baseline: 1.0224x; 1.0224x over previous
//
#include <hip/hip_runtime.h>

#define BATCH   1024
#define MAXLEN  200
#define KCAPS   8
#define INU     256
#define OUTU    256
#define NEGPAD  -65535.0f
#define HSTR    264   // padded LDS row stride (floats)

typedef _Float16 f16;
typedef _Float16 f16x8 __attribute__((ext_vector_type(8)));
typedef float    f32x4 __attribute__((ext_vector_type(4)));
typedef float    f32x2 __attribute__((ext_vector_type(2)));

// ---------------- prep: Bcur copy + packed-frag S and S^T (hi/lo f16) ------
__global__ void k_prep(const float* __restrict__ S, const float* __restrict__ Bm,
                       f16* __restrict__ Shi, f16* __restrict__ Slo,
                       f16* __restrict__ Thi, f16* __restrict__ Tlo,
                       float* __restrict__ Bcur) {
    int idx = blockIdx.x * 256 + threadIdx.x;    // 0 .. 65535
    if (idx < KCAPS * MAXLEN) Bcur[idx] = Bm[idx];
    int j    = idx & 7;
    int lane = (idx >> 3) & 63;
    int nf   = (idx >> 9) & 15;
    int ks   = idx >> 13;
    int k = ks * 32 + (lane >> 4) * 8 + j;
    int n = nf * 16 + (lane & 15);
    float vS = S[k * 256 + n];
    f16 hS = (f16)vS;
    Shi[idx] = hS;
    Slo[idx] = (f16)(vS - (float)hS);
    float vT = S[n * 256 + k];
    f16 hT = (f16)vT;
    Thi[idx] = hT;
    Tlo[idx] = (f16)(vT - (float)hT);
}

// phase-E fragment: delta rows MF*16+r15, all 8 ks, burst-loaded
#define EFRAG(MF, ACC) do {                                                          \
    const int l_  = (MF) * 16 + r15;                                                 \
    const int lc_ = (l_ < MAXLEN) ? l_ : (MAXLEN - 1);                               \
    const float* ap_ = lb + (size_t)lc_ * INU + q * 8;                               \
    f32x4 va[8], vb[8];                                                              \
    _Pragma("unroll")                                                                \
    for (int ks = 0; ks < 8; ks++) {                                                 \
        va[ks] = *reinterpret_cast<const f32x4*>(ap_ + ks * 32);                     \
        vb[ks] = *reinterpret_cast<const f32x4*>(ap_ + ks * 32 + 4);                 \
    }                                                                                \
    _Pragma("unroll")                                                                \
    for (int ks = 0; ks < 8; ks++) {                                                 \
        const int ob_ = ks * 32 + q * 8;                                             \
        f32x4 h0 = *reinterpret_cast<const f32x4*>(&GH[r15 * HSTR + ob_]);           \
        f32x4 h1 = *reinterpret_cast<const f32x4*>(&GH[r15 * HSTR + ob_ + 4]);       \
        f16x8 bh, bl, ah, al;                                                        \
        _Pragma("unroll")                                                            \
        for (int j = 0; j < 4; j++) { f16 t = (f16)h0[j]; bh[j] = t; bl[j] = (f16)(h0[j] - (float)t); } \
        _Pragma("unroll")                                                            \
        for (int j = 0; j < 4; j++) { f16 t = (f16)h1[j]; bh[4+j] = t; bl[4+j] = (f16)(h1[j] - (float)t); } \
        _Pragma("unroll")                                                            \
        for (int j = 0; j < 4; j++) { f16 t = (f16)va[ks][j]; ah[j] = t; al[j] = (f16)(va[ks][j] - (float)t); } \
        _Pragma("unroll")                                                            \
        for (int j = 0; j < 4; j++) { f16 t = (f16)vb[ks][j]; ah[4+j] = t; al[4+j] = (f16)(vb[ks][j] - (float)t); } \
        ACC = __builtin_amdgcn_mfma_f32_16x16x32_f16(ah, bh, ACC, 0, 0, 0);          \
        ACC = __builtin_amdgcn_mfma_f32_16x16x32_f16(al, bh, ACC, 0, 0, 0);          \
        ACC = __builtin_amdgcn_mfma_f32_16x16x32_f16(ah, bl, ACC, 0, 0, 0);          \
    }                                                                                \
} while (0)

// ---------------- fused per-iteration kernel --------------------------------
__global__ __launch_bounds__(512, 4) void k_G(const float* __restrict__ Bcur,
                                              const int*   __restrict__ seq_len,
                                              const float* __restrict__ low,
                                              const f16*   __restrict__ Shi,
                                              const f16*   __restrict__ Slo,
                                              const f16*   __restrict__ Thi,
                                              const f16*   __restrict__ Tlo,
                                              float*       __restrict__ partials,
                                              float*       __restrict__ out,
                                              int do_T) {
    __shared__ float Wl[KCAPS * MAXLEN];     // 6.4 KB
    __shared__ float GH[16 * HSTR];          // 16.9 KB: Gl -> Hl -> Tl (rows 8..15 stay 0)
    __shared__ float Sl2[2 * KCAPS * 256];   // 16 KB reduce slab (2 regions)
    const int b   = blockIdx.x;
    const int tid = threadIdx.x;
    const int len = seq_len[b];

    for (int i = tid; i < KCAPS * MAXLEN; i += 512) Wl[i] = Bcur[i];
    for (int i = tid; i < 16 * HSTR; i += 512) GH[i] = 0.f;
    __syncthreads();

    // phase A: masked softmax, one 64-lane wave per k
    {
        const int k  = tid >> 6;
        const int ln = tid & 63;
        float m = -3.4e38f;
        for (int l = ln; l < MAXLEN; l += 64) {
            float v = (l < len) ? Wl[k * MAXLEN + l] : NEGPAD;
            m = fmaxf(m, v);
        }
        #pragma unroll
        for (int off = 32; off >= 1; off >>= 1) m = fmaxf(m, __shfl_xor(m, off));
        float ssum = 0.f;
        for (int l = ln; l < MAXLEN; l += 64) {
            float v = (l < len) ? Wl[k * MAXLEN + l] : NEGPAD;
            ssum += __expf(v - m);
        }
        #pragma unroll
        for (int off = 32; off >= 1; off >>= 1) ssum += __shfl_xor(ssum, off);
        float inv = 1.f / ssum;
        for (int l = ln; l < MAXLEN; l += 64) {
            float v = (l < len) ? Wl[k * MAXLEN + l] : NEGPAD;
            Wl[k * MAXLEN + l] = __expf(v - m) * inv;
        }
    }
    __syncthreads();

    const float* lb = low + (size_t)b * (MAXLEN * INU);

    // phase B: G[k,c] = sum_l W[k,l]*low[l,c].  128 col-pairs x 4 row-groups,
    // float2 loads (512B/wave-instr), wave-uniform W broadcast, 2-round reduce.
    {
        const int cp = tid & 127;            // col-pair
        const int rg = tid >> 7;             // row group 0..3 (wave-uniform)
        const int lim = (len == 0) ? MAXLEN : len;
        const float* cb = lb + cp * 2;
        f32x2 g[KCAPS];
        #pragma unroll
        for (int k = 0; k < KCAPS; k++) g[k] = (f32x2){0.f, 0.f};
        int l = rg;
        for (; l + 4 < lim; l += 8) {
            f32x2 va = *reinterpret_cast<const f32x2*>(cb + l * INU);
            f32x2 vb = *reinterpret_cast<const f32x2*>(cb + (l + 4) * INU);
            #pragma unroll
            for (int k = 0; k < KCAPS; k++) {
                float wa = Wl[k * MAXLEN + l];
                float wb = Wl[k * MAXLEN + l + 4];
                g[k][0] = fmaf(wa, va[0], g[k][0]);
                g[k][1] = fmaf(wa, va[1], g[k][1]);
                g[k][0] = fmaf(wb, vb[0], g[k][0]);
                g[k][1] = fmaf(wb, vb[1], g[k][1]);
            }
        }
        if (l < lim) {
            f32x2 va = *reinterpret_cast<const f32x2*>(cb + l * INU);
            #pragma unroll
            for (int k = 0; k < KCAPS; k++) {
                float wa = Wl[k * MAXLEN + l];
                g[k][0] = fmaf(wa, va[0], g[k][0]);
                g[k][1] = fmaf(wa, va[1], g[k][1]);
            }
        }
        // reduce 4 groups -> GH rows 0..7
        if (rg >= 2) {
            #pragma unroll
            for (int k = 0; k < KCAPS; k++)
                *reinterpret_cast<f32x2*>(&Sl2[((rg - 2) * KCAPS + k) * 256 + cp * 2]) = g[k];
        }
        __syncthreads();
        if (rg == 1) {
            #pragma unroll
            for (int k = 0; k < KCAPS; k++) {
                f32x2 t = *reinterpret_cast<f32x2*>(&Sl2[(KCAPS + k) * 256 + cp * 2]);
                g[k][0] += t[0]; g[k][1] += t[1];
                *reinterpret_cast<f32x2*>(&Sl2[(KCAPS + k) * 256 + cp * 2]) = g[k];
            }
        } else if (rg == 0) {
            #pragma unroll
            for (int k = 0; k < KCAPS; k++) {
                f32x2 t = *reinterpret_cast<f32x2*>(&Sl2[k * 256 + cp * 2]);
                g[k][0] += t[0]; g[k][1] += t[1];
            }
        }
        __syncthreads();
        if (rg == 0) {
            #pragma unroll
            for (int k = 0; k < KCAPS; k++) {
                f32x2 t = *reinterpret_cast<f32x2*>(&Sl2[(KCAPS + k) * 256 + cp * 2]);
                GH[k * HSTR + cp * 2]     = g[k][0] + t[0];
                GH[k * HSTR + cp * 2 + 1] = g[k][1] + t[1];
            }
        }
    }
    __syncthreads();

    // phase C (MFMA): hp[k][o] = sum_e G[k][e]*S[e][o]; wave wv -> nf = 2wv, 2wv+1
    const int wv = tid >> 6, lane = tid & 63;
    const int r15 = lane & 15, q = lane >> 4;
    f32x4 aC[2];
    aC[0] = (f32x4){0.f, 0.f, 0.f, 0.f};
    aC[1] = (f32x4){0.f, 0.f, 0.f, 0.f};
    #pragma unroll
    for (int ks = 0; ks < 8; ks++) {
        const float* gp = &GH[r15 * HSTR + ks * 32 + q * 8];
        f32x4 a0 = *reinterpret_cast<const f32x4*>(gp);
        f32x4 a1 = *reinterpret_cast<const f32x4*>(gp + 4);
        f16x8 ah, al;
        #pragma unroll
        for (int j = 0; j < 4; j++) {
            f16 t = (f16)a0[j]; ah[j] = t; al[j] = (f16)(a0[j] - (float)t);
        }
        #pragma unroll
        for (int j = 0; j < 4; j++) {
            f16 t = (f16)a1[j]; ah[4 + j] = t; al[4 + j] = (f16)(a1[j] - (float)t);
        }
        #pragma unroll
        for (int i = 0; i < 2; i++) {
            const int nf = wv * 2 + i;
            f16x8 bh = *reinterpret_cast<const f16x8*>(Shi + (ks * 16 + nf) * 512 + lane * 8);
            f16x8 bl = *reinterpret_cast<const f16x8*>(Slo + (ks * 16 + nf) * 512 + lane * 8);
            aC[i] = __builtin_amdgcn_mfma_f32_16x16x32_f16(ah, bh, aC[i], 0, 0, 0);
            aC[i] = __builtin_amdgcn_mfma_f32_16x16x32_f16(al, bh, aC[i], 0, 0, 0);
            aC[i] = __builtin_amdgcn_mfma_f32_16x16x32_f16(ah, bl, aC[i], 0, 0, 0);
        }
    }
    // squash: thread holds hp[k=q*4+r][o=(2wv+i)*16+r15]; k<8 lives in q=0,1
    float s0, s1;
    {
        float n0 = aC[0][0]*aC[0][0] + aC[0][1]*aC[0][1] + aC[0][2]*aC[0][2] + aC[0][3]*aC[0][3];
        float n1 = aC[1][0]*aC[1][0] + aC[1][1]*aC[1][1] + aC[1][2]*aC[1][2] + aC[1][3]*aC[1][3];
        n0 += __shfl_xor(n0, 16);
        n1 += __shfl_xor(n1, 16);
        s0 = n0 / (1.f + n0) * (1.f / sqrtf(n0 + 1e-9f));
        s1 = n1 / (1.f + n1) * (1.f / sqrtf(n1 + 1e-9f));
    }
    if (!do_T) {
        if (q < 2) {
            #pragma unroll
            for (int r = 0; r < 4; r++) {
                out[((size_t)b * KCAPS + q * 4 + r) * OUTU + (wv * 2 + 0) * 16 + r15] = s0 * aC[0][r];
                out[((size_t)b * KCAPS + q * 4 + r) * OUTU + (wv * 2 + 1) * 16 + r15] = s1 * aC[1][r];
            }
        }
        return;
    }
    __syncthreads();                       // all phase-C reads of GH done
    if (q < 2) {                           // GH becomes Hl (rows 8..15 still 0)
        #pragma unroll
        for (int r = 0; r < 4; r++) {
            GH[(q * 4 + r) * HSTR + (wv * 2 + 0) * 16 + r15] = s0 * aC[0][r];
            GH[(q * 4 + r) * HSTR + (wv * 2 + 1) * 16 + r15] = s1 * aC[1][r];
        }
    }
    __syncthreads();

    // phase D (MFMA): T[k][e] = sum_o H[k][o]*S[e][o]
    f32x4 aD[2];
    aD[0] = (f32x4){0.f, 0.f, 0.f, 0.f};
    aD[1] = (f32x4){0.f, 0.f, 0.f, 0.f};
    #pragma unroll
    for (int ks = 0; ks < 8; ks++) {
        const float* hp = &GH[r15 * HSTR + ks * 32 + q * 8];
        f32x4 a0 = *reinterpret_cast<const f32x4*>(hp);
        f32x4 a1 = *reinterpret_cast<const f32x4*>(hp + 4);
        f16x8 ah, al;
        #pragma unroll
        for (int j = 0; j < 4; j++) {
            f16 t = (f16)a0[j]; ah[j] = t; al[j] = (f16)(a0[j] - (float)t);
        }
        #pragma unroll
        for (int j = 0; j < 4; j++) {
            f16 t = (f16)a1[j]; ah[4 + j] = t; al[4 + j] = (f16)(a1[j] - (float)t);
        }
        #pragma unroll
        for (int i = 0; i < 2; i++) {
            const int nf = wv * 2 + i;
            f16x8 bh = *reinterpret_cast<const f16x8*>(Thi + (ks * 16 + nf) * 512 + lane * 8);
            f16x8 bl = *reinterpret_cast<const f16x8*>(Tlo + (ks * 16 + nf) * 512 + lane * 8);
            aD[i] = __builtin_amdgcn_mfma_f32_16x16x32_f16(ah, bh, aD[i], 0, 0, 0);
            aD[i] = __builtin_amdgcn_mfma_f32_16x16x32_f16(al, bh, aD[i], 0, 0, 0);
            aD[i] = __builtin_amdgcn_mfma_f32_16x16x32_f16(ah, bl, aD[i], 0, 0, 0);
        }
    }
    __syncthreads();                       // all phase-D reads of GH done
    if (q < 2) {                           // GH becomes Tl (rows 8..15 still 0)
        #pragma unroll
        for (int r = 0; r < 4; r++) {
            GH[(q * 4 + r) * HSTR + (wv * 2 + 0) * 16 + r15] = aD[0][r];
            GH[(q * 4 + r) * HSTR + (wv * 2 + 1) * 16 + r15] = aD[1][r];
        }
    }
    __syncthreads();

    // phase E (MFMA): delta_T[l][k] = sum_e low[l,e]*T[k,e]; named accs (no
    // runtime-indexed reg arrays), per-frag 16x16B load burst.
    f32x4 accA = (f32x4){0.f, 0.f, 0.f, 0.f};
    f32x4 accB = (f32x4){0.f, 0.f, 0.f, 0.f};
    EFRAG(wv, accA);
    if (wv < 5) EFRAG(wv + 8, accB);

    if (r15 < KCAPS) {
        const int kcol = r15;
        {   // frag A rows: l = wv*16 + q*4 + r  (max 127 < 200, no guard)
            const int lbase = wv * 16 + q * 4;
            #pragma unroll
            for (int r = 0; r < 4; r++)
                partials[(size_t)(kcol * MAXLEN + lbase + r) * BATCH + b] = accA[r];
        }
        if (wv < 5) {   // frag B rows: l = (wv+8)*16 + q*4 + r (may exceed 199)
            const int lbase = (wv + 8) * 16 + q * 4;
            #pragma unroll
            for (int r = 0; r < 4; r++) {
                const int l = lbase + r;
                if (l < MAXLEN)
                    partials[(size_t)(kcol * MAXLEN + l) * BATCH + b] = accB[r];
            }
        }
    }
}

// ---------------- B update: Bcur[i] += sum_b partials[i][b] ----------------
__global__ __launch_bounds__(256) void k_update(const float* __restrict__ partials,
                                                float* __restrict__ Bcur) {
    __shared__ float red[256];
    const int i   = blockIdx.x;
    const int tid = threadIdx.x;
    float s = 0.f;
    #pragma unroll
    for (int j = 0; j < BATCH / 256; j++) s += partials[(size_t)i * BATCH + tid + j * 256];
    red[tid] = s;
    __syncthreads();
    for (int st = 128; st > 0; st >>= 1) {
        if (tid < st) red[tid] += red[tid + st];
        __syncthreads();
    }
    if (tid == 0) Bcur[i] += red[0];
}

extern "C" void kernel_launch(void* const* d_in, const int* in_sizes, int n_in,
                              void* d_out, int out_size, void* d_ws, size_t ws_size,
                              hipStream_t stream) {
    const float* low = (const float*)d_in[0];
    const float* S   = (const float*)d_in[1];
    const float* Bm  = (const float*)d_in[2];
    const int*   seq = (const int*)d_in[3];
    float* out = (float*)d_out;

    char* ws = (char*)d_ws;
    float* Bcur     = (float*)ws;                     // 6,400 B
    float* partials = (float*)(ws + 6400);            // 6,553,600 B
    f16*   Shi      = (f16*)(ws + 6560000);           // 131,072 B
    f16*   Slo      = (f16*)(ws + 6691072);           // 131,072 B
    f16*   Thi      = (f16*)(ws + 6822144);           // 131,072 B
    f16*   Tlo      = (f16*)(ws + 6953216);           // 131,072 B

    k_prep<<<256, 256, 0, stream>>>(S, Bm, Shi, Slo, Thi, Tlo, Bcur);
    for (int it = 0; it < 3; it++) {
        int last = (it == 2);
        k_G<<<BATCH, 512, 0, stream>>>(Bcur, seq, low, Shi, Slo, Thi, Tlo,
                                       partials, out, last ? 0 : 1);
        if (!last) k_update<<<KCAPS * MAXLEN, 256, 0, stream>>>(partials, Bcur);
    }
}